// Round 2
// baseline (1312.010 us; speedup 1.0000x reference)
//
#include <hip/hip_runtime.h>

#define EMB 512
#define HEADS 8
#define KD 64
#define SEQ 2048
#define BATCH 4

// ---------------------------------------------------------------------------
// Projection GEMM: out[M,512] = in[M,512] @ W[512,512]
// TRANSQ=1: scatter output to [B, H, S, 64] (Q projection)
// TRANSQ=0: dense row-major output (output projection; safe in-place because
//           each block stages its 8 input rows in LDS before writing them)
// ---------------------------------------------------------------------------
template <int TRANSQ>
__global__ __launch_bounds__(256) void proj_kernel(const float* __restrict__ in,
                                                   const float* __restrict__ W,
                                                   float* __restrict__ out) {
    __shared__ float x_s[8][EMB];  // 16 KB
    const int block_row = blockIdx.x * 8;

    // stage 8 input rows (4096 floats) with float4 loads
    const float4* in4 = (const float4*)(in + (size_t)block_row * EMB);
    float4* xs4 = (float4*)(&x_s[0][0]);
    for (int i = threadIdx.x; i < 8 * EMB / 4; i += 256) xs4[i] = in4[i];
    __syncthreads();

    const int n  = (threadIdx.x & 127) * 4;  // output col 0..508
    const int rg = threadIdx.x >> 7;         // 0 or 1

    float acc[4][4] = {};
    for (int e = 0; e < EMB; ++e) {
        const float4 w4 = *(const float4*)(W + (size_t)e * EMB + n);
#pragma unroll
        for (int rr = 0; rr < 4; ++rr) {
            const float xv = x_s[rg + rr * 2][e];  // same addr across wave -> broadcast
            acc[rr][0] += xv * w4.x;
            acc[rr][1] += xv * w4.y;
            acc[rr][2] += xv * w4.z;
            acc[rr][3] += xv * w4.w;
        }
    }

#pragma unroll
    for (int rr = 0; rr < 4; ++rr) {
        const int row = block_row + rg + rr * 2;  // global row in [0, B*S)
        float4 o;
        o.x = acc[rr][0]; o.y = acc[rr][1]; o.z = acc[rr][2]; o.w = acc[rr][3];
        if (TRANSQ) {
            const int b = row >> 11;        // row / 2048
            const int s = row & 2047;
            const int h = n >> 6;
            const int k = n & 63;
            *(float4*)(out + (((size_t)(b * HEADS + h) * SEQ + s) * KD + k)) = o;
        } else {
            *(float4*)(out + (size_t)row * EMB + n) = o;
        }
    }
}

// ---------------------------------------------------------------------------
// Flash attention: one block per (b*h, 16-query-row tile). fp32 vector ALU.
// Q:[B,H,S,64] (pre-scaled here by 1/8), K/V:[B,H,S,64], ctx -> [B,S,H*64]
// ---------------------------------------------------------------------------
__global__ __launch_bounds__(256) void attn_kernel(const float* __restrict__ Q,
                                                   const float* __restrict__ Keys,
                                                   const float* __restrict__ Vals,
                                                   float* __restrict__ ctx) {
    constexpr int QB = 16;
    constexpr int KB = 128;

    __shared__ float q_s[QB][65];    // pad 65: bank = (r+k)%32, conflict-free
    __shared__ float k_s[KB][65];    // pad 65: bank = (s+k)%32, conflict-free
    __shared__ float v_s[KB][64];    // uniform s per instr -> <=2-way (free)
    __shared__ float p_s[QB][129];   // pad 129: <=2-way on write, bcast on read
    __shared__ float red_s[QB][17];
    __shared__ float m_s[QB], l_s[QB], scale_s[QB];

    const int bh = blockIdx.y;            // 0..31
    const int q0 = blockIdx.x * QB;
    const float* qbase = Q + ((size_t)bh * SEQ + q0) * KD;
    const float* kbase = Keys + (size_t)bh * SEQ * KD;
    const float* vbase = Vals + (size_t)bh * SEQ * KD;

    const int t = threadIdx.x;

    // load Q tile, apply 1/sqrt(64)
    for (int i = t; i < QB * KD; i += 256) {
        q_s[i >> 6][i & 63] = qbase[i] * 0.125f;
    }
    if (t < QB) { m_s[t] = -1e30f; l_s[t] = 0.0f; }

    const int r  = t & 15;        // score row
    const int g  = t >> 4;        // 0..15
    const int sb = g * 8;         // score s-base (covers 0..127)
    const int r2 = t >> 4;        // PV row 0..15
    const int c  = (t & 15) * 4;  // PV col 0..60

    float acc[4] = {0.f, 0.f, 0.f, 0.f};

    for (int tile = 0; tile < SEQ / KB; ++tile) {
        __syncthreads();  // protect k_s/v_s/p_s/red_s from previous iteration

        // ---- stage K,V tile (128x64 each) ----
        const float4* kt = (const float4*)(kbase + (size_t)tile * KB * KD);
        const float4* vt = (const float4*)(vbase + (size_t)tile * KB * KD);
        for (int i = t; i < KB * KD / 4; i += 256) {
            const float4 kv = kt[i];
            const int f = i * 4;
            const int s = f >> 6, k = f & 63;
            k_s[s][k] = kv.x; k_s[s][k + 1] = kv.y;
            k_s[s][k + 2] = kv.z; k_s[s][k + 3] = kv.w;
            ((float4*)&v_s[0][0])[i] = vt[i];
        }
        __syncthreads();

        // ---- scores: row r, s = sb..sb+7 ----
        float sc[8] = {};
        for (int k = 0; k < KD; ++k) {
            const float qv = q_s[r][k];
#pragma unroll
            for (int j = 0; j < 8; ++j) sc[j] += qv * k_s[sb + j][k];
        }

        // ---- tile max ----
        float pm = sc[0];
#pragma unroll
        for (int j = 1; j < 8; ++j) pm = fmaxf(pm, sc[j]);
        red_s[r][g] = pm;
        __syncthreads();
        if (t < QB) {
            float tm = red_s[t][0];
            for (int i = 1; i < 16; ++i) tm = fmaxf(tm, red_s[t][i]);
            const float mo = m_s[t];
            const float mn = fmaxf(mo, tm);
            scale_s[t] = __expf(mo - mn);
            m_s[t] = mn;
        }
        __syncthreads();

        // ---- exp + partial sums, write P ----
        const float mn = m_s[r];
        float ps = 0.f;
#pragma unroll
        for (int j = 0; j < 8; ++j) {
            const float p = __expf(sc[j] - mn);
            p_s[r][sb + j] = p;
            ps += p;
        }
        red_s[r][g] = ps;
        __syncthreads();
        if (t < QB) {
            float ssum = 0.f;
            for (int i = 0; i < 16; ++i) ssum += red_s[t][i];
            l_s[t] = l_s[t] * scale_s[t] + ssum;
        }

        // ---- PV accumulate (scale_s/p_s valid; l_s not needed until end) ----
        const float sc2 = scale_s[r2];
        acc[0] *= sc2; acc[1] *= sc2; acc[2] *= sc2; acc[3] *= sc2;
        for (int s = 0; s < KB; ++s) {
            const float pv = p_s[r2][s];
            acc[0] += pv * v_s[s][c];
            acc[1] += pv * v_s[s][c + 1];
            acc[2] += pv * v_s[s][c + 2];
            acc[3] += pv * v_s[s][c + 3];
        }
    }
    __syncthreads();  // l_s final

    const float inv_l = 1.0f / l_s[r2];
    const int b = bh >> 3, h = bh & 7;
    float4 o;
    o.x = acc[0] * inv_l; o.y = acc[1] * inv_l;
    o.z = acc[2] * inv_l; o.w = acc[3] * inv_l;
    *(float4*)(ctx + ((size_t)(b * SEQ + q0 + r2) * EMB) + h * KD + c) = o;
}

// ---------------------------------------------------------------------------
extern "C" void kernel_launch(void* const* d_in, const int* in_sizes, int n_in,
                              void* d_out, int out_size, void* d_ws, size_t ws_size,
                              hipStream_t stream) {
    const float* x  = (const float*)d_in[0];   // [B,S,512]
    const float* ks = (const float*)d_in[1];   // [B,H,S,64]
    const float* vs = (const float*)d_in[2];   // [B,H,S,64]
    const float* wq = (const float*)d_in[3];   // [512,512]
    const float* wo = (const float*)d_in[4];   // [512,512]
    float* out = (float*)d_out;                // [B,S,512]

    float* Q = (float*)d_ws;                   // 16 MB scratch: [B,H,S,64]

    const int M = BATCH * SEQ;  // 8192

    // 1) Q = x @ Wq  (scattered to [B,H,S,64])
    proj_kernel<1><<<dim3(M / 8), dim3(256), 0, stream>>>(x, wq, Q);

    // 2) flash attention -> ctx in d_out as [B,S,H*64]
    attn_kernel<<<dim3(SEQ / 16, BATCH * HEADS), dim3(256), 0, stream>>>(Q, ks, vs, out);

    // 3) out = ctx @ Wo, in place on d_out
    proj_kernel<0><<<dim3(M / 8), dim3(256), 0, stream>>>(out, wo, out);
}

// Round 5
// 380.803 us; speedup vs baseline: 3.4454x; 3.4454x over previous
//
#include <hip/hip_runtime.h>
#include <hip/hip_bf16.h>

#define EMB 512
#define HEADS 8
#define KD 64
#define SEQ 2048
#define BATCH 4

typedef __attribute__((ext_vector_type(8))) short bf16x8;
typedef __attribute__((ext_vector_type(4))) float f32x4;

__device__ __forceinline__ unsigned short f2bf(float x) {
    union { float f; unsigned u; } v; v.f = x;
    unsigned r = v.u + 0x7fff + ((v.u >> 16) & 1);   // RNE
    return (unsigned short)(r >> 16);
}
__device__ __forceinline__ float bf2f(unsigned short b) {
    union { unsigned u; float f; } v; v.u = ((unsigned)b) << 16;
    return v.f;
}

// ---------------------------------------------------------------------------
// Projection GEMM: out[M,512] = in[M,512] @ W[512,512]  (fp32 vector ALU)
// TRANSQ=1: scatter output to [B, H, S, 64] (Q projection)
// ---------------------------------------------------------------------------
template <int TRANSQ>
__global__ __launch_bounds__(256) void proj_kernel(const float* __restrict__ in,
                                                   const float* __restrict__ W,
                                                   float* __restrict__ out) {
    __shared__ float x_s[8][EMB];
    const int block_row = blockIdx.x * 8;

    const float4* in4 = (const float4*)(in + (size_t)block_row * EMB);
    float4* xs4 = (float4*)(&x_s[0][0]);
    for (int i = threadIdx.x; i < 8 * EMB / 4; i += 256) xs4[i] = in4[i];
    __syncthreads();

    const int n  = (threadIdx.x & 127) * 4;
    const int rg = threadIdx.x >> 7;

    float acc[4][4] = {};
    for (int e = 0; e < EMB; ++e) {
        const float4 w4 = *(const float4*)(W + (size_t)e * EMB + n);
#pragma unroll
        for (int rr = 0; rr < 4; ++rr) {
            const float xv = x_s[rg + rr * 2][e];
            acc[rr][0] += xv * w4.x;
            acc[rr][1] += xv * w4.y;
            acc[rr][2] += xv * w4.z;
            acc[rr][3] += xv * w4.w;
        }
    }

#pragma unroll
    for (int rr = 0; rr < 4; ++rr) {
        const int row = block_row + rg + rr * 2;
        float4 o;
        o.x = acc[rr][0]; o.y = acc[rr][1]; o.z = acc[rr][2]; o.w = acc[rr][3];
        if (TRANSQ) {
            const int b = row >> 11;
            const int s = row & 2047;
            const int h = n >> 6;
            const int k = n & 63;
            *(float4*)(out + (((size_t)(b * HEADS + h) * SEQ + s) * KD + k)) = o;
        } else {
            *(float4*)(out + (size_t)row * EMB + n) = o;
        }
    }
}

// ---------------------------------------------------------------------------
// MFMA flash attention, split-bf16 (hi+lo) QK^T for near-fp32 score accuracy.
// Block = 4 waves x 16 q-rows. KV tile NT=64. Swapped QK^T (S^T = K·Q^T).
// S ~= k_lo*q_hi + k_hi*q_lo + k_hi*q_hi  (lo*lo dropped, ~2^-18 relative).
// ---------------------------------------------------------------------------
__global__ __launch_bounds__(256) void attn_mfma_kernel(const float* __restrict__ Q,
                                                        const float* __restrict__ Keys,
                                                        const float* __restrict__ Vals,
                                                        float* __restrict__ out) {
    constexpr int NT  = 64;
    constexpr int LDK = 72;   // bf16 row stride: 144B -> 16B-aligned b128 reads

    __shared__ unsigned short k_s[2][NT][LDK];   // K tile [hi/lo][s][d]
    __shared__ unsigned short v_t[KD][LDK];      // V^T tile [d][s]
    __shared__ unsigned short p_s[4][16][LDK];   // per-wave P [q][s]

    const int t  = threadIdx.x;
    const int w  = t >> 6;
    const int l  = t & 63;
    const int g  = l >> 4;
    const int ln = l & 15;

    const int bh = blockIdx.y;
    const int q0 = blockIdx.x * 64 + w * 16;

    const float* qptr  = Q + ((size_t)bh * SEQ + q0 + ln) * KD;
    const float* kbase = Keys + (size_t)bh * SEQ * KD;
    const float* vbase = Vals + (size_t)bh * SEQ * KD;

    // Q fragments hi+lo (B-operand: col q = ln, k = d = g*8+j+32kk), pre-scaled 1/8
    bf16x8 qhi[2], qlo[2];
#pragma unroll
    for (int kk = 0; kk < 2; ++kk) {
        const float* p = qptr + g * 8 + 32 * kk;
#pragma unroll
        for (int j = 0; j < 8; ++j) {
            const float x = p[j] * 0.125f;
            const unsigned short h = f2bf(x);
            qhi[kk][j] = (short)h;
            qlo[kk][j] = (short)f2bf(x - bf2f(h));
        }
    }

    f32x4 acc[4];
#pragma unroll
    for (int db = 0; db < 4; ++db) acc[db] = (f32x4){0.f, 0.f, 0.f, 0.f};
    float m_run = -1e30f, l_run = 0.0f;

    for (int tile = 0; tile < SEQ / NT; ++tile) {
        __syncthreads();   // all waves done with previous k_s/v_t

        const float* kt = kbase + (size_t)tile * NT * KD;
        const float* vt = vbase + (size_t)tile * NT * KD;

        // ---- stage K row-major bf16 hi+lo ----
#pragma unroll
        for (int it = 0; it < 4; ++it) {
            const int idx = t + it * 256;          // 0..1023
            const int s   = idx >> 4;
            const int d4  = (idx & 15) << 2;
            const float4 kv = *(const float4*)(kt + s * KD + d4);
            unsigned short h0 = f2bf(kv.x), h1 = f2bf(kv.y),
                           h2 = f2bf(kv.z), h3 = f2bf(kv.w);
            *(uint2*)&k_s[0][s][d4] = make_uint2(
                (unsigned)h0 | ((unsigned)h1 << 16),
                (unsigned)h2 | ((unsigned)h3 << 16));
            *(uint2*)&k_s[1][s][d4] = make_uint2(
                (unsigned)f2bf(kv.x - bf2f(h0)) | ((unsigned)f2bf(kv.y - bf2f(h1)) << 16),
                (unsigned)f2bf(kv.z - bf2f(h2)) | ((unsigned)f2bf(kv.w - bf2f(h3)) << 16));
        }
        // ---- stage V transposed: pack 2 bf16 along s -> b32 writes, 2-way banks ----
#pragma unroll
        for (int it = 0; it < 2; ++it) {
            const int idx = t + it * 256;          // 0..511
            const int sp  = idx & 31;              // s-pair index
            const int d4  = (idx >> 5) << 2;       // 0..60
            const float* v0 = vt + (2 * sp) * KD + d4;
            const float4 a = *(const float4*)v0;
            const float4 b = *(const float4*)(v0 + KD);
#pragma unroll
            for (int j = 0; j < 4; ++j) {
                const float aj = (&a.x)[j], bj = (&b.x)[j];
                *(unsigned*)&v_t[d4 + j][2 * sp] =
                    (unsigned)f2bf(aj) | ((unsigned)f2bf(bj) << 16);
            }
        }
        __syncthreads();

        // ---- S^T[64][16] = K · Q^T, split-bf16 (small terms first) ----
        f32x4 st[4];
#pragma unroll
        for (int sb = 0; sb < 4; ++sb) {
            f32x4 c = (f32x4){0.f, 0.f, 0.f, 0.f};
#pragma unroll
            for (int kk = 0; kk < 2; ++kk) {
                const bf16x8 khi = *(const bf16x8*)&k_s[0][sb * 16 + ln][g * 8 + 32 * kk];
                const bf16x8 klo = *(const bf16x8*)&k_s[1][sb * 16 + ln][g * 8 + 32 * kk];
                c = __builtin_amdgcn_mfma_f32_16x16x32_bf16(klo, qhi[kk], c, 0, 0, 0);
                c = __builtin_amdgcn_mfma_f32_16x16x32_bf16(khi, qlo[kk], c, 0, 0, 0);
                c = __builtin_amdgcn_mfma_f32_16x16x32_bf16(khi, qhi[kk], c, 0, 0, 0);
            }
            st[sb] = c;   // value S^T[16sb+4g+r][q=ln]
        }

        // ---- online softmax over s for q=ln: 16 in-lane + shfl_xor(16,32) ----
        float tm = st[0][0];
#pragma unroll
        for (int sb = 0; sb < 4; ++sb)
#pragma unroll
            for (int r = 0; r < 4; ++r) tm = fmaxf(tm, st[sb][r]);
        tm = fmaxf(tm, __shfl_xor(tm, 16));
        tm = fmaxf(tm, __shfl_xor(tm, 32));

        const float m_new  = fmaxf(m_run, tm);
        const float scalef = __expf(m_run - m_new);
        m_run = m_new;

        float rs = 0.f;
#pragma unroll
        for (int sb = 0; sb < 4; ++sb) {
            const float p0 = __expf(st[sb][0] - m_new);
            const float p1 = __expf(st[sb][1] - m_new);
            const float p2 = __expf(st[sb][2] - m_new);
            const float p3 = __expf(st[sb][3] - m_new);
            rs += (p0 + p1) + (p2 + p3);
            const unsigned lo = (unsigned)f2bf(p0) | ((unsigned)f2bf(p1) << 16);
            const unsigned hi = (unsigned)f2bf(p2) | ((unsigned)f2bf(p3) << 16);
            *(uint2*)&p_s[w][ln][sb * 16 + g * 4] = make_uint2(lo, hi);
        }
        rs += __shfl_xor(rs, 16);
        rs += __shfl_xor(rs, 32);
        l_run = l_run * scalef + rs;

        // ---- rescale acc (acc row q = 4g+r; scale lives at lane q) ----
#pragma unroll
        for (int r = 0; r < 4; ++r) {
            const float sr = __shfl(scalef, 4 * g + r);
#pragma unroll
            for (int db = 0; db < 4; ++db) acc[db][r] *= sr;
        }

        // ---- PV: ctx[16q][64d] += P · V ; A=P from p_s, B=V^T rows ----
        bf16x8 pa[2];
#pragma unroll
        for (int kk = 0; kk < 2; ++kk)
            pa[kk] = *(const bf16x8*)&p_s[w][ln][g * 8 + 32 * kk];
#pragma unroll
        for (int db = 0; db < 4; ++db) {
            f32x4 c = acc[db];
#pragma unroll
            for (int kk = 0; kk < 2; ++kk) {
                const bf16x8 vb = *(const bf16x8*)&v_t[ln + 16 * db][g * 8 + 32 * kk];
                c = __builtin_amdgcn_mfma_f32_16x16x32_bf16(pa[kk], vb, c, 0, 0, 0);
            }
            acc[db] = c;
        }
    }

    // ---- epilogue: normalize, write ctx rows ----
    const float invl = 1.0f / l_run;
    const int b = bh >> 3, h = bh & 7;
#pragma unroll
    for (int r = 0; r < 4; ++r) {
        const float iv = __shfl(invl, 4 * g + r);
        float* orow = out + ((size_t)(b * SEQ + q0 + 4 * g + r) * EMB) + h * KD + ln;
#pragma unroll
        for (int db = 0; db < 4; ++db) orow[16 * db] = acc[db][r] * iv;
    }
}

// ---------------------------------------------------------------------------
extern "C" void kernel_launch(void* const* d_in, const int* in_sizes, int n_in,
                              void* d_out, int out_size, void* d_ws, size_t ws_size,
                              hipStream_t stream) {
    const float* x  = (const float*)d_in[0];
    const float* ks = (const float*)d_in[1];
    const float* vs = (const float*)d_in[2];
    const float* wq = (const float*)d_in[3];
    const float* wo = (const float*)d_in[4];
    float* out = (float*)d_out;

    float* Q = (float*)d_ws;   // [B,H,S,64] fp32

    const int M = BATCH * SEQ;

    proj_kernel<1><<<dim3(M / 8), dim3(256), 0, stream>>>(x, wq, Q);
    attn_mfma_kernel<<<dim3(SEQ / 64, BATCH * HEADS), dim3(256), 0, stream>>>(Q, ks, vs, out);
    proj_kernel<0><<<dim3(M / 8), dim3(256), 0, stream>>>(out, wo, out);
}

// Round 6
// 313.294 us; speedup vs baseline: 4.1878x; 1.2155x over previous
//
#include <hip/hip_runtime.h>
#include <hip/hip_bf16.h>

#define EMB 512
#define HEADS 8
#define KD 64
#define SEQ 2048
#define BATCH 4

typedef __attribute__((ext_vector_type(8))) short bf16x8;
typedef __attribute__((ext_vector_type(4))) float f32x4;

__device__ __forceinline__ unsigned short f2bf(float x) {
    union { float f; unsigned u; } v; v.f = x;
    unsigned r = v.u + 0x7fff + ((v.u >> 16) & 1);   // RNE
    return (unsigned short)(r >> 16);
}
__device__ __forceinline__ float bf2f(unsigned short b) {
    union { unsigned u; float f; } v; v.u = ((unsigned)b) << 16;
    return v.f;
}

// ---------------------------------------------------------------------------
// Old fp32 projection (kept as ws-too-small fallback for the out-projection:
// 8-row blocks stage all 512 cols before writing -> in-place safe).
// ---------------------------------------------------------------------------
__global__ __launch_bounds__(256) void proj_fp32_kernel(const float* __restrict__ in,
                                                        const float* __restrict__ W,
                                                        float* __restrict__ out) {
    __shared__ float x_s[8][EMB];
    const int block_row = blockIdx.x * 8;

    const float4* in4 = (const float4*)(in + (size_t)block_row * EMB);
    float4* xs4 = (float4*)(&x_s[0][0]);
    for (int i = threadIdx.x; i < 8 * EMB / 4; i += 256) xs4[i] = in4[i];
    __syncthreads();

    const int n  = (threadIdx.x & 127) * 4;
    const int rg = threadIdx.x >> 7;

    float acc[4][4] = {};
    for (int e = 0; e < EMB; ++e) {
        const float4 w4 = *(const float4*)(W + (size_t)e * EMB + n);
#pragma unroll
        for (int rr = 0; rr < 4; ++rr) {
            const float xv = x_s[rg + rr * 2][e];
            acc[rr][0] += xv * w4.x;
            acc[rr][1] += xv * w4.y;
            acc[rr][2] += xv * w4.z;
            acc[rr][3] += xv * w4.w;
        }
    }
#pragma unroll
    for (int rr = 0; rr < 4; ++rr) {
        const int row = block_row + rg + rr * 2;
        float4 o;
        o.x = acc[rr][0]; o.y = acc[rr][1]; o.z = acc[rr][2]; o.w = acc[rr][3];
        *(float4*)(out + (size_t)row * EMB + n) = o;
    }
}

// ---------------------------------------------------------------------------
// MFMA projection GEMM, split-bf16 (3-term) for near-fp32 accuracy.
// out[M,512] = in[M,512] @ W[512,512]. Tile 64x64, BK=64, 4 waves.
// TRANSQ=1: scatter output to [B,H,S,64] (Q projection).
// NOT in-place safe (col-slice writers vs row readers) -> needs distinct out.
// ---------------------------------------------------------------------------
template <int TRANSQ>
__global__ __launch_bounds__(256) void proj_mfma_kernel(const float* __restrict__ in,
                                                        const float* __restrict__ W,
                                                        float* __restrict__ out) {
    __shared__ unsigned short x_s[2][64][72];   // [hi/lo][row][k]
    __shared__ unsigned short w_t[2][64][72];   // [hi/lo][col][k]

    const int t  = threadIdx.x;
    const int w  = t >> 6;
    const int l  = t & 63;
    const int g  = l >> 4;
    const int ln = l & 15;

    const int row0 = blockIdx.x * 64;
    const int n0   = blockIdx.y * 64;

    f32x4 acc[4];
#pragma unroll
    for (int cb = 0; cb < 4; ++cb) acc[cb] = (f32x4){0.f, 0.f, 0.f, 0.f};

    for (int ch = 0; ch < EMB / 64; ++ch) {
        __syncthreads();

        // ---- stage x tile [64 rows][64 k] hi+lo (coalesced float4 reads) ----
#pragma unroll
        for (int it = 0; it < 4; ++it) {
            const int idx = t + it * 256;          // 0..1023
            const int s   = idx >> 4;
            const int d4  = (idx & 15) << 2;
            const float4 xv = *(const float4*)(in + (size_t)(row0 + s) * EMB + ch * 64 + d4);
            const unsigned short h0 = f2bf(xv.x), h1 = f2bf(xv.y),
                                 h2 = f2bf(xv.z), h3 = f2bf(xv.w);
            *(uint2*)&x_s[0][s][d4] = make_uint2(
                (unsigned)h0 | ((unsigned)h1 << 16),
                (unsigned)h2 | ((unsigned)h3 << 16));
            *(uint2*)&x_s[1][s][d4] = make_uint2(
                (unsigned)f2bf(xv.x - bf2f(h0)) | ((unsigned)f2bf(xv.y - bf2f(h1)) << 16),
                (unsigned)f2bf(xv.z - bf2f(h2)) | ((unsigned)f2bf(xv.w - bf2f(h3)) << 16));
        }
        // ---- stage W transposed [64 cols][64 k] hi+lo (pack 2 along k) ----
#pragma unroll
        for (int it = 0; it < 2; ++it) {
            const int idx = t + it * 256;          // 0..511
            const int sp  = idx & 31;              // k-pair index
            const int c4  = (idx >> 5) << 2;       // col 0..60
            const float* wrow = W + (size_t)(ch * 64 + 2 * sp) * EMB + n0 + c4;
            const float4 a = *(const float4*)wrow;
            const float4 b = *(const float4*)(wrow + EMB);
#pragma unroll
            for (int j = 0; j < 4; ++j) {
                const float aj = (&a.x)[j], bj = (&b.x)[j];
                const unsigned short ah = f2bf(aj), bh = f2bf(bj);
                *(unsigned*)&w_t[0][c4 + j][2 * sp] =
                    (unsigned)ah | ((unsigned)bh << 16);
                *(unsigned*)&w_t[1][c4 + j][2 * sp] =
                    (unsigned)f2bf(aj - bf2f(ah)) | ((unsigned)f2bf(bj - bf2f(bh)) << 16);
            }
        }
        __syncthreads();

        // ---- compute: A rows = w*16+ln, 4 col-blocks, 3-term split ----
        bf16x8 ah[2], al[2];
#pragma unroll
        for (int kk = 0; kk < 2; ++kk) {
            ah[kk] = *(const bf16x8*)&x_s[0][w * 16 + ln][g * 8 + 32 * kk];
            al[kk] = *(const bf16x8*)&x_s[1][w * 16 + ln][g * 8 + 32 * kk];
        }
#pragma unroll
        for (int cb = 0; cb < 4; ++cb) {
            f32x4 c = acc[cb];
#pragma unroll
            for (int kk = 0; kk < 2; ++kk) {
                const bf16x8 bh = *(const bf16x8*)&w_t[0][cb * 16 + ln][g * 8 + 32 * kk];
                const bf16x8 bl = *(const bf16x8*)&w_t[1][cb * 16 + ln][g * 8 + 32 * kk];
                c = __builtin_amdgcn_mfma_f32_16x16x32_bf16(al[kk], bh, c, 0, 0, 0);
                c = __builtin_amdgcn_mfma_f32_16x16x32_bf16(ah[kk], bl, c, 0, 0, 0);
                c = __builtin_amdgcn_mfma_f32_16x16x32_bf16(ah[kk], bh, c, 0, 0, 0);
            }
            acc[cb] = c;
        }
    }

    // ---- epilogue: C row = 4g+r (wave rows w*16..+15), col = cb*16+ln ----
#pragma unroll
    for (int cb = 0; cb < 4; ++cb) {
#pragma unroll
        for (int r = 0; r < 4; ++r) {
            const int row = row0 + w * 16 + 4 * g + r;
            const int col = n0 + cb * 16 + ln;
            if (TRANSQ) {
                const int b = row >> 11, s = row & 2047;
                const int h = col >> 6, k = col & 63;
                out[((size_t)(b * HEADS + h) * SEQ + s) * KD + k] = acc[cb][r];
            } else {
                out[(size_t)row * EMB + col] = acc[cb][r];
            }
        }
    }
}

// ---------------------------------------------------------------------------
// MFMA flash attention, split-bf16 (hi+lo) QK^T. (unchanged from round 5)
// ---------------------------------------------------------------------------
__global__ __launch_bounds__(256) void attn_mfma_kernel(const float* __restrict__ Q,
                                                        const float* __restrict__ Keys,
                                                        const float* __restrict__ Vals,
                                                        float* __restrict__ out) {
    constexpr int NT  = 64;
    constexpr int LDK = 72;

    __shared__ unsigned short k_s[2][NT][LDK];
    __shared__ unsigned short v_t[KD][LDK];
    __shared__ unsigned short p_s[4][16][LDK];

    const int t  = threadIdx.x;
    const int w  = t >> 6;
    const int l  = t & 63;
    const int g  = l >> 4;
    const int ln = l & 15;

    const int bh = blockIdx.y;
    const int q0 = blockIdx.x * 64 + w * 16;

    const float* qptr  = Q + ((size_t)bh * SEQ + q0 + ln) * KD;
    const float* kbase = Keys + (size_t)bh * SEQ * KD;
    const float* vbase = Vals + (size_t)bh * SEQ * KD;

    bf16x8 qhi[2], qlo[2];
#pragma unroll
    for (int kk = 0; kk < 2; ++kk) {
        const float* p = qptr + g * 8 + 32 * kk;
#pragma unroll
        for (int j = 0; j < 8; ++j) {
            const float x = p[j] * 0.125f;
            const unsigned short h = f2bf(x);
            qhi[kk][j] = (short)h;
            qlo[kk][j] = (short)f2bf(x - bf2f(h));
        }
    }

    f32x4 acc[4];
#pragma unroll
    for (int db = 0; db < 4; ++db) acc[db] = (f32x4){0.f, 0.f, 0.f, 0.f};
    float m_run = -1e30f, l_run = 0.0f;

    for (int tile = 0; tile < SEQ / NT; ++tile) {
        __syncthreads();

        const float* kt = kbase + (size_t)tile * NT * KD;
        const float* vt = vbase + (size_t)tile * NT * KD;

#pragma unroll
        for (int it = 0; it < 4; ++it) {
            const int idx = t + it * 256;
            const int s   = idx >> 4;
            const int d4  = (idx & 15) << 2;
            const float4 kv = *(const float4*)(kt + s * KD + d4);
            unsigned short h0 = f2bf(kv.x), h1 = f2bf(kv.y),
                           h2 = f2bf(kv.z), h3 = f2bf(kv.w);
            *(uint2*)&k_s[0][s][d4] = make_uint2(
                (unsigned)h0 | ((unsigned)h1 << 16),
                (unsigned)h2 | ((unsigned)h3 << 16));
            *(uint2*)&k_s[1][s][d4] = make_uint2(
                (unsigned)f2bf(kv.x - bf2f(h0)) | ((unsigned)f2bf(kv.y - bf2f(h1)) << 16),
                (unsigned)f2bf(kv.z - bf2f(h2)) | ((unsigned)f2bf(kv.w - bf2f(h3)) << 16));
        }
#pragma unroll
        for (int it = 0; it < 2; ++it) {
            const int idx = t + it * 256;
            const int sp  = idx & 31;
            const int d4  = (idx >> 5) << 2;
            const float* v0 = vt + (2 * sp) * KD + d4;
            const float4 a = *(const float4*)v0;
            const float4 b = *(const float4*)(v0 + KD);
#pragma unroll
            for (int j = 0; j < 4; ++j) {
                const float aj = (&a.x)[j], bj = (&b.x)[j];
                *(unsigned*)&v_t[d4 + j][2 * sp] =
                    (unsigned)f2bf(aj) | ((unsigned)f2bf(bj) << 16);
            }
        }
        __syncthreads();

        f32x4 st[4];
#pragma unroll
        for (int sb = 0; sb < 4; ++sb) {
            f32x4 c = (f32x4){0.f, 0.f, 0.f, 0.f};
#pragma unroll
            for (int kk = 0; kk < 2; ++kk) {
                const bf16x8 khi = *(const bf16x8*)&k_s[0][sb * 16 + ln][g * 8 + 32 * kk];
                const bf16x8 klo = *(const bf16x8*)&k_s[1][sb * 16 + ln][g * 8 + 32 * kk];
                c = __builtin_amdgcn_mfma_f32_16x16x32_bf16(klo, qhi[kk], c, 0, 0, 0);
                c = __builtin_amdgcn_mfma_f32_16x16x32_bf16(khi, qlo[kk], c, 0, 0, 0);
                c = __builtin_amdgcn_mfma_f32_16x16x32_bf16(khi, qhi[kk], c, 0, 0, 0);
            }
            st[sb] = c;
        }

        float tm = st[0][0];
#pragma unroll
        for (int sb = 0; sb < 4; ++sb)
#pragma unroll
            for (int r = 0; r < 4; ++r) tm = fmaxf(tm, st[sb][r]);
        tm = fmaxf(tm, __shfl_xor(tm, 16));
        tm = fmaxf(tm, __shfl_xor(tm, 32));

        const float m_new  = fmaxf(m_run, tm);
        const float scalef = __expf(m_run - m_new);
        m_run = m_new;

        float rs = 0.f;
#pragma unroll
        for (int sb = 0; sb < 4; ++sb) {
            const float p0 = __expf(st[sb][0] - m_new);
            const float p1 = __expf(st[sb][1] - m_new);
            const float p2 = __expf(st[sb][2] - m_new);
            const float p3 = __expf(st[sb][3] - m_new);
            rs += (p0 + p1) + (p2 + p3);
            const unsigned lo = (unsigned)f2bf(p0) | ((unsigned)f2bf(p1) << 16);
            const unsigned hi = (unsigned)f2bf(p2) | ((unsigned)f2bf(p3) << 16);
            *(uint2*)&p_s[w][ln][sb * 16 + g * 4] = make_uint2(lo, hi);
        }
        rs += __shfl_xor(rs, 16);
        rs += __shfl_xor(rs, 32);
        l_run = l_run * scalef + rs;

#pragma unroll
        for (int r = 0; r < 4; ++r) {
            const float sr = __shfl(scalef, 4 * g + r);
#pragma unroll
            for (int db = 0; db < 4; ++db) acc[db][r] *= sr;
        }

        bf16x8 pa[2];
#pragma unroll
        for (int kk = 0; kk < 2; ++kk)
            pa[kk] = *(const bf16x8*)&p_s[w][ln][g * 8 + 32 * kk];
#pragma unroll
        for (int db = 0; db < 4; ++db) {
            f32x4 c = acc[db];
#pragma unroll
            for (int kk = 0; kk < 2; ++kk) {
                const bf16x8 vb = *(const bf16x8*)&v_t[ln + 16 * db][g * 8 + 32 * kk];
                c = __builtin_amdgcn_mfma_f32_16x16x32_bf16(pa[kk], vb, c, 0, 0, 0);
            }
            acc[db] = c;
        }
    }

    const float invl = 1.0f / l_run;
    const int b = bh >> 3, h = bh & 7;
#pragma unroll
    for (int r = 0; r < 4; ++r) {
        const float iv = __shfl(invl, 4 * g + r);
        float* orow = out + ((size_t)(b * SEQ + q0 + 4 * g + r) * EMB) + h * KD + ln;
#pragma unroll
        for (int db = 0; db < 4; ++db) orow[16 * db] = acc[db][r] * iv;
    }
}

// ---------------------------------------------------------------------------
extern "C" void kernel_launch(void* const* d_in, const int* in_sizes, int n_in,
                              void* d_out, int out_size, void* d_ws, size_t ws_size,
                              hipStream_t stream) {
    const float* x  = (const float*)d_in[0];
    const float* ks = (const float*)d_in[1];
    const float* vs = (const float*)d_in[2];
    const float* wq = (const float*)d_in[3];
    const float* wo = (const float*)d_in[4];
    float* out = (float*)d_out;

    const size_t QBYTES = (size_t)BATCH * HEADS * SEQ * KD * sizeof(float);  // 16.8 MB
    const size_t CBYTES = (size_t)BATCH * SEQ * EMB * sizeof(float);         // 16.8 MB
    float* Q = (float*)d_ws;
    const bool big_ws = ws_size >= QBYTES + CBYTES;
    float* ctx = big_ws ? (float*)((char*)d_ws + QBYTES) : out;

    const int M = BATCH * SEQ;  // 8192

    // 1) Q = x @ Wq (MFMA split-bf16), scattered to [B,H,S,64]
    proj_mfma_kernel<1><<<dim3(M / 64, EMB / 64), dim3(256), 0, stream>>>(x, wq, Q);

    // 2) flash attention -> ctx [B,S,512]
    attn_mfma_kernel<<<dim3(SEQ / 64, BATCH * HEADS), dim3(256), 0, stream>>>(Q, ks, vs, ctx);

    // 3) out = ctx @ Wo
    if (big_ws) {
        proj_mfma_kernel<0><<<dim3(M / 64, EMB / 64), dim3(256), 0, stream>>>(ctx, wo, out);
    } else {
        proj_fp32_kernel<<<dim3(M / 8), dim3(256), 0, stream>>>(ctx, wo, out);  // in-place safe
    }
}